// Round 6
// baseline (192.973 us; speedup 1.0000x reference)
//
#include <hip/hip_runtime.h>

#define BB   4
#define SS   1024
#define DD   1024
#define HH   16
#define DHH  64
#define LN_EPS  (1e-3f)

typedef unsigned short u16;
typedef __attribute__((ext_vector_type(8))) short bf16x8;
typedef __attribute__((ext_vector_type(4))) float f32x4;

__device__ __forceinline__ u16 f2bf(float f) {
    union { float f; unsigned int u; } v; v.f = f;
    return (u16)((v.u + 0x7FFFu + ((v.u >> 16) & 1u)) >> 16);
}

// pack two f32 -> two bf16 (RNE) in one VALU op
__device__ __forceinline__ unsigned int cvt_pk_bf16(float lo, float hi) {
    unsigned int r;
    asm("v_cvt_pk_bf16_f32 %0, %1, %2" : "=v"(r) : "v"(lo), "v"(hi));
    return r;
}

// async global->LDS, 16B per lane; lane i lands at lds + i*16 (wave-uniform
// base, no per-lane scatter — swizzle is applied to the SOURCE address).
__device__ __forceinline__ void cp16(void* lds, const void* g) {
    __builtin_amdgcn_global_load_lds(
        (const __attribute__((address_space(1))) unsigned int*)g,
        (__attribute__((address_space(3))) unsigned int*)lds, 16, 0, 0);
}

// ---------------------------------------------------------------------------
// prep: z<3 -> fp32->bf16 convert of queries/keys/values into Abf[3][4096][1024]
//       z>=3 -> W[k][n] fp32 -> Wt[n][k] bf16 (transpose+convert)
// ---------------------------------------------------------------------------
__global__ __launch_bounds__(256) void prep(const float* __restrict__ q,
                                            const float* __restrict__ k,
                                            const float* __restrict__ v,
                                            const float* __restrict__ Wq,
                                            const float* __restrict__ Wk,
                                            const float* __restrict__ Wv,
                                            u16* __restrict__ Abf,
                                            u16* __restrict__ WtA) {
    __shared__ float Ts[64][65];
    const int z = blockIdx.z;
    const int tid = threadIdx.x;
    if (z < 3) {
        const float* src = (z == 0) ? q : (z == 1) ? k : v;
        u16* dst = Abf + (size_t)z * ((size_t)BB * SS * DD);
        const int N8 = BB * SS * DD / 8;
        for (int i = blockIdx.x * 256 + tid; i < N8; i += 256 * 256) {
            const float4 f0 = ((const float4*)src)[i * 2];
            const float4 f1 = ((const float4*)src)[i * 2 + 1];
            union { u16 u[8]; uint4 o; } t;
            t.u[0] = f2bf(f0.x); t.u[1] = f2bf(f0.y);
            t.u[2] = f2bf(f0.z); t.u[3] = f2bf(f0.w);
            t.u[4] = f2bf(f1.x); t.u[5] = f2bf(f1.y);
            t.u[6] = f2bf(f1.z); t.u[7] = f2bf(f1.w);
            ((uint4*)dst)[i] = t.o;
        }
    } else {
        const float* W = (z == 3) ? Wq : (z == 4) ? Wk : Wv;
        u16* Wt = WtA + (size_t)(z - 3) * DD * DD;
        const int k0 = (blockIdx.x >> 4) * 64, n0 = (blockIdx.x & 15) * 64;
        #pragma unroll
        for (int it = 0; it < 4; ++it) {
            const int idx = tid + it * 256;
            const int r = idx >> 4, c4 = (idx & 15) * 4;
            const float4 vv = *(const float4*)&W[(size_t)(k0 + r) * DD + n0 + c4];
            Ts[r][c4 + 0] = vv.x; Ts[r][c4 + 1] = vv.y;
            Ts[r][c4 + 2] = vv.z; Ts[r][c4 + 3] = vv.w;
        }
        __syncthreads();
        const int n = tid >> 2, kc = (tid & 3) * 16;
        #pragma unroll
        for (int p = 0; p < 8; ++p) {
            const unsigned int lo = f2bf(Ts[kc + p * 2 + 0][n]);
            const unsigned int hi = f2bf(Ts[kc + p * 2 + 1][n]);
            *(unsigned int*)&Wt[(size_t)(n0 + n) * DD + k0 + kc + p * 2] = lo | (hi << 16);
        }
    }
}

// ---------------------------------------------------------------------------
// Fused QKV projection GEMM — 128x128 tile, BK=64, 4 waves (2x2), 256 thr.
// m97 structure: single-buffer LDS (32 KB), global_load_lds staging, 2
// barriers per K-step. __launch_bounds__(256,3) forces <=170 regs/wave ->
// 3 blocks/CU co-resident (12 waves/CU): cross-block overlap hides the
// barrier drain (m114).
// Grid = 768 blocks (3z x 32m x 8n), XCD-swizzled, = 3 clean rounds.
//   z=0: Q*(0.125*log2e) [b][h][s][dh] (exp2-domain); z=1: K; z=2: V^T.
// ---------------------------------------------------------------------------
__global__ __launch_bounds__(256, 3) void gemm_fused(const u16* __restrict__ Abf,
                                                     const u16* __restrict__ WtA,
                                                     u16* __restrict__ Qbf,
                                                     u16* __restrict__ Kbf,
                                                     u16* __restrict__ Vtb) {
    __shared__ u16 As[128 * 64];   // 16 KB, XOR-swizzled chunks
    __shared__ u16 Bs[128 * 64];

    const int bid = blockIdx.x;
    const int swz = (bid & 7) * 96 + (bid >> 3);   // bijective, 768 % 8 == 0
    const int z   = swz >> 8;                      // 256 tiles per z
    const int rem = swz & 255;
    const int m0  = (rem >> 3) * 128;              // m-major within XCD: B panels reused
    const int n0  = (rem & 7) * 128;

    const u16* A  = Abf + (size_t)z * ((size_t)BB * SS * DD);
    const u16* Bm = WtA + (size_t)z * (DD * DD);

    const int tid  = threadIdx.x;
    const int wave = tid >> 6, lane = tid & 63;
    const int ln = lane & 15, quad = lane >> 4;
    const int mw = (wave & 1) * 64, nw = (wave >> 1) * 64;

    // staging decomposition for slot l = w*256+tid: row r = w*32 + (tid>>3),
    // stored chunk cs = tid&7 holds global chunk c = cs ^ (r&7); r&7 and c
    // are w-invariant (w*32 % 8 == 0) -> single base + uniform w offset.
    const int r0 = tid >> 3;
    const int c0 = (tid & 7) ^ (r0 & 7);
    const u16* srcA0 = A  + (size_t)(m0 + r0) * DD + c0 * 8;
    const u16* srcB0 = Bm + (size_t)(n0 + r0) * DD + c0 * 8;

    f32x4 acc[4][4] = {};

    for (int t = 0; t < 16; ++t) {
        const int koff = t * 64;
        __syncthreads();
        #pragma unroll
        for (int w = 0; w < 4; ++w) {
            cp16(&As[(w * 256 + wave * 64) * 8], srcA0 + (size_t)w * 32 * DD + koff);
            cp16(&Bs[(w * 256 + wave * 64) * 8], srcB0 + (size_t)w * 32 * DD + koff);
        }
        __syncthreads();

        #pragma unroll
        for (int kk = 0; kk < 2; ++kk) {
            bf16x8 af[4], bfv[4];
            #pragma unroll
            for (int i = 0; i < 4; ++i) {
                const int r = mw + i * 16 + ln;
                af[i] = *(const bf16x8*)&As[((r << 3) + ((kk * 4 + quad) ^ (r & 7))) << 3];
            }
            #pragma unroll
            for (int j = 0; j < 4; ++j) {
                const int r = nw + j * 16 + ln;
                bfv[j] = *(const bf16x8*)&Bs[((r << 3) + ((kk * 4 + quad) ^ (r & 7))) << 3];
            }
            __builtin_amdgcn_s_setprio(1);
            #pragma unroll
            for (int i = 0; i < 4; ++i)
                #pragma unroll
                for (int j = 0; j < 4; ++j)
                    acc[i][j] = __builtin_amdgcn_mfma_f32_16x16x32_bf16(af[i], bfv[j], acc[i][j], 0, 0, 0);
            __builtin_amdgcn_s_setprio(0);
        }
    }

    if (z < 2) {
        u16* C = (z == 0) ? Qbf : Kbf;
        // z=0: fold 1/sqrt(64) AND log2(e) into Q so attn uses exp2 directly
        const float scale = (z == 0) ? 0.18033688f : 1.0f;
        #pragma unroll
        for (int i = 0; i < 4; ++i) {
            const int mbase = m0 + mw + i * 16 + quad * 4;
            const int bb = mbase >> 10, sb = mbase & 1023;
            #pragma unroll
            for (int j = 0; j < 4; ++j) {
                const int n = n0 + nw + j * 16 + ln;
                const int hh = n >> 6, dh = n & 63;
                #pragma unroll
                for (int r = 0; r < 4; ++r)
                    C[(((size_t)bb * HH + hh) * SS + sb + r) * DHH + dh] =
                        f2bf(acc[i][j][r] * scale);
            }
        }
    } else {
        #pragma unroll
        for (int i = 0; i < 4; ++i) {
            const int mbase = m0 + mw + i * 16 + quad * 4;
            const int bb = mbase >> 10, sb = mbase & 1023;
            #pragma unroll
            for (int j = 0; j < 4; ++j) {
                const int n = n0 + nw + j * 16 + ln;
                const int hh = n >> 6, dh = n & 63;
                uint2 pk;
                pk.x = cvt_pk_bf16(acc[i][j][0], acc[i][j][1]);
                pk.y = cvt_pk_bf16(acc[i][j][2], acc[i][j][3]);
                *(uint2*)&Vtb[(((size_t)bb * HH + hh) * DHH + dh) * SS + sb] = pk;
            }
        }
    }
}

// ---------------------------------------------------------------------------
// Flash attention. 4 waves (256 thr), QBLK=128 -> 32 q-rows per wave (two
// verified 16-row fragments: qf[2][2], o[2][4], lsum[2]). KVBLK=64. Each
// staged K/V tile now feeds 2x the MFMA per wave (LDS bytes/FLOP halved)
// and each wave carries two independent q-set chains (ILP). Grid = 512
// blocks = 2 blocks/CU (LDS 53.4KB); barriers lockstep only half a CU's
// waves -> cross-block overlap covers stage drains. K/V double-buffered,
// counted vmcnt(4) (never 0 mid-loop), raw s_barrier. Swapped QK^T
// (mfma(K,Q)) -> lane-local P segment, cvt_pk + ds_write_b64 to Ps.
// Q direct global->reg. kmask staged once as floats.
// ---------------------------------------------------------------------------
__global__ __launch_bounds__(256) void attn_mfma(const u16* __restrict__ Qg,
                                                 const u16* __restrict__ Kg,
                                                 const u16* __restrict__ Vtg,
                                                 const int* __restrict__ qmask,
                                                 const int* __restrict__ kmask,
                                                 float* __restrict__ O) {
    __shared__ u16 Ps[128 * 68];         // P spill, pitch 68
    __shared__ u16 Ks[2][64 * 64];       // [key][dh] swizzled chunks, dbuf
    __shared__ u16 Vs[2][64 * 64];       // [dh][key] swizzled chunks, dbuf
    __shared__ float kmLds[SS];          // key-mask as float 0/1

    const int bid  = blockIdx.x;
    const int xcd  = bid & 7;
    const int rest = bid >> 3;               // 0..63
    const int bh   = (rest & 7) * 8 + xcd;   // 0..63, bh%8==xcd
    const int qt   = rest >> 3;              // 0..7
    const int b    = bh >> 4, h = bh & 15;
    const int q0   = qt * 128;
    const int tid  = threadIdx.x;
    const int wave = tid >> 6, lane = tid & 63;
    const int ln = lane & 15, quad = lane >> 4;
    const size_t bhs = (size_t)b * HH + h;

    // staging: 256 threads x 16B x 2 rounds = 8KB = one 64x64 bf16 tile each.
    // slot l = rd*256+tid: row r = rd*32 + (tid>>3), chunk cs = tid&7,
    // source chunk = cs ^ (r&7); r&7 == (tid>>3)&7 (rd*32 % 8 == 0).
    const int sr  = tid >> 3;                       // 0..31
    const int scs = (tid & 7) ^ (sr & 7);
    const u16* kS = &Kg[(bhs * SS + sr) * DHH + scs * 8];
    const u16* vS = &Vtg[(bhs * DHH + sr) * SS + scs * 8];
    auto stageKV = [&](int t) {
        const int cb = t & 1;
        #pragma unroll
        for (int rd = 0; rd < 2; ++rd) {
            cp16(&Ks[cb][(rd * 256 + wave * 64) * 8], kS + ((size_t)t * 64 + rd * 32) * DHH);
            cp16(&Vs[cb][(rd * 256 + wave * 64) * 8], vS + (size_t)rd * 32 * SS + t * 64);
        }
    };

    // --- prologue ---
    // Q fragments direct to registers: rows q0 + wave*32 + qs*16 + ln
    const u16* qbase = &Qg[(bhs * SS + q0 + wave * 32 + ln) * DHH];
    bf16x8 qf[2][2];
    qf[0][0] = *(const bf16x8*)&qbase[quad * 8];
    qf[0][1] = *(const bf16x8*)&qbase[32 + quad * 8];
    qf[1][0] = *(const bf16x8*)&qbase[16 * DHH + quad * 8];
    qf[1][1] = *(const bf16x8*)&qbase[16 * DHH + 32 + quad * 8];
    asm volatile("" ::: "memory");       // pin qf issue before staging
    cp16(&kmLds[wave * 256], &kmask[b * SS + tid * 4]);
    stageKV(0);
    stageKV(1);
    asm volatile("s_waitcnt vmcnt(4)" ::: "memory");   // qf+km+tile0 landed
    __builtin_amdgcn_s_barrier();

    // kmask int -> float in place (each thread owns 4)
    {
        const int4 iv = *(const int4*)&kmLds[tid * 4];
        float4 fv;
        fv.x = (float)iv.x; fv.y = (float)iv.y;
        fv.z = (float)iv.z; fv.w = (float)iv.w;
        *(float4*)&kmLds[tid * 4] = fv;
    }
    asm volatile("s_waitcnt lgkmcnt(0)" ::: "memory");
    __builtin_amdgcn_s_barrier();

    // hoisted swizzled LDS element offsets: row nt*16+ln, chunk kk*4+quad
    int off[4][2];
    #pragma unroll
    for (int nt = 0; nt < 4; ++nt) {
        const int r = nt * 16 + ln;
        off[nt][0] = ((r << 3) + ((0 + quad) ^ (r & 7))) << 3;
        off[nt][1] = ((r << 3) + ((4 + quad) ^ (r & 7))) << 3;
    }

    f32x4 o[2][4] = {};
    float lsum[2] = {0.f, 0.f};
    const f32x4 zero = {0.f, 0.f, 0.f, 0.f};
    const int prow0 = (wave * 32 + ln) * 68;        // qs=0 row base
    const int prow1 = (wave * 32 + 16 + ln) * 68;   // qs=1 row base

    #pragma unroll 2
    for (int kt = 0; kt < SS / 64; ++kt) {
        const int cb = kt & 1;
        const u16* Kc = Ks[cb];
        const u16* Vc = Vs[cb];

        // S^T = K @ Q^T (Q pre-scaled by 0.125*log2e); p = fm * exp2(s)
        // out: k-row = nt*16 + quad*4 + r, q-col = (qs set) + ln
        #pragma unroll
        for (int qs = 0; qs < 2; ++qs) {
            const int prow = qs ? prow1 : prow0;
            #pragma unroll
            for (int nt = 0; nt < 4; ++nt) {
                const bf16x8 k0f = *(const bf16x8*)&Kc[off[nt][0]];
                const bf16x8 k1f = *(const bf16x8*)&Kc[off[nt][1]];
                f32x4 sacc = __builtin_amdgcn_mfma_f32_16x16x32_bf16(k0f, qf[qs][0], zero, 0, 0, 0);
                sacc = __builtin_amdgcn_mfma_f32_16x16x32_bf16(k1f, qf[qs][1], sacc, 0, 0, 0);
                const float4 fm = *(const float4*)&kmLds[kt * 64 + nt * 16 + quad * 4];
                const float p0 = fm.x * __builtin_amdgcn_exp2f(sacc[0]);
                const float p1 = fm.y * __builtin_amdgcn_exp2f(sacc[1]);
                const float p2 = fm.z * __builtin_amdgcn_exp2f(sacc[2]);
                const float p3 = fm.w * __builtin_amdgcn_exp2f(sacc[3]);
                lsum[qs] += (p0 + p1) + (p2 + p3);
                uint2 pk;
                pk.x = cvt_pk_bf16(p0, p1);
                pk.y = cvt_pk_bf16(p2, p3);
                *(uint2*)&Ps[prow + nt * 16 + quad * 4] = pk;   // 4 consecutive cols
            }
        }
        // Ps rows are wave-private; same-wave lgkm ordering covers the RAW.

        // O += P @ V  (both q-sets)
        __builtin_amdgcn_s_setprio(1);
        #pragma unroll
        for (int qs = 0; qs < 2; ++qs) {
            const int prow = qs ? prow1 : prow0;
            #pragma unroll
            for (int kk2 = 0; kk2 < 2; ++kk2) {
                const bf16x8 pf = *(const bf16x8*)&Ps[prow + kk2 * 32 + quad * 8];
                #pragma unroll
                for (int nt2 = 0; nt2 < 4; ++nt2) {
                    const bf16x8 vf = *(const bf16x8*)&Vc[off[nt2][kk2]];
                    o[qs][nt2] = __builtin_amdgcn_mfma_f32_16x16x32_bf16(pf, vf, o[qs][nt2], 0, 0, 0);
                }
            }
        }
        __builtin_amdgcn_s_setprio(0);

        if (kt == SS / 64 - 1) break;
        __builtin_amdgcn_s_barrier();        // all waves done reading buf cb
        if (kt + 2 < SS / 64) {
            stageKV(kt + 2);                 // overwrite buf cb
            asm volatile("s_waitcnt vmcnt(4)" ::: "memory");   // tile kt+1 landed
        } else {
            asm volatile("s_waitcnt vmcnt(0)" ::: "memory");   // last stage drain
        }
        __builtin_amdgcn_s_barrier();
    }

    // epilogue: quad-reduce lane-local l (q = qset + ln), normalize, store
    #pragma unroll
    for (int qs = 0; qs < 2; ++qs) {
        lsum[qs] += __shfl_xor(lsum[qs], 16);
        lsum[qs] += __shfl_xor(lsum[qs], 32);
        #pragma unroll
        for (int r = 0; r < 4; ++r) {
            const int qloc = quad * 4 + r;
            const float l = __shfl(lsum[qs], qloc);    // lane qloc holds full sum
            const int q = q0 + wave * 32 + qs * 16 + qloc;
            const float scale = (float)qmask[b * SS + q] / l;
            #pragma unroll
            for (int nt2 = 0; nt2 < 4; ++nt2)
                O[((size_t)b * SS + q) * DD + h * DHH + nt2 * 16 + ln] = o[qs][nt2][r] * scale;
        }
    }
}

// ---------------------------------------------------------------------------
// residual + LayerNorm over D=1024. One block (256 thr) per (b,s) row.
// ---------------------------------------------------------------------------
__global__ __launch_bounds__(256) void ln_kernel(const float* __restrict__ Qin,
                                                 const float* __restrict__ attn,
                                                 const float* __restrict__ gamma,
                                                 const float* __restrict__ beta,
                                                 float* __restrict__ out) {
    const int row = blockIdx.x;
    const int tid = threadIdx.x;
    const int wid = tid >> 6, lane = tid & 63;
    __shared__ float sred[4];

    const float4 qv = ((const float4*)Qin)[(size_t)row * 256 + tid];
    const float4 av = ((const float4*)attn)[(size_t)row * 256 + tid];
    float4 v;
    v.x = qv.x + av.x; v.y = qv.y + av.y;
    v.z = qv.z + av.z; v.w = qv.w + av.w;

    float sum = v.x + v.y + v.z + v.w;
    #pragma unroll
    for (int off = 32; off; off >>= 1) sum += __shfl_down(sum, off);
    if (lane == 0) sred[wid] = sum;
    __syncthreads();
    const float mean = (sred[0] + sred[1] + sred[2] + sred[3]) * (1.0f / DD);
    __syncthreads();

    const float dx = v.x - mean, dy = v.y - mean, dz = v.z - mean, dw = v.w - mean;
    float vs = dx * dx + dy * dy + dz * dz + dw * dw;
    #pragma unroll
    for (int off = 32; off; off >>= 1) vs += __shfl_down(vs, off);
    if (lane == 0) sred[wid] = vs;
    __syncthreads();
    const float var = (sred[0] + sred[1] + sred[2] + sred[3]) * (1.0f / DD);
    const float inv = rsqrtf(var + LN_EPS);

    const float4 g = ((const float4*)gamma)[tid];
    const float4 bt = ((const float4*)beta)[tid];
    float4 ov;
    ov.x = g.x * dx * inv + bt.x; ov.y = g.y * dy * inv + bt.y;
    ov.z = g.z * dz * inv + bt.z; ov.w = g.w * dw * inv + bt.w;
    ((float4*)out)[(size_t)row * 256 + tid] = ov;
}

// ---------------------------------------------------------------------------
extern "C" void kernel_launch(void* const* d_in, const int* in_sizes, int n_in,
                              void* d_out, int out_size, void* d_ws, size_t ws_size,
                              hipStream_t stream) {
    const float* queries = (const float*)d_in[0];
    const float* keys    = (const float*)d_in[1];
    const float* values  = (const float*)d_in[2];
    const int*   qmask   = (const int*)d_in[3];
    const int*   kmask   = (const int*)d_in[4];
    const float* Wq      = (const float*)d_in[5];
    const float* Wk      = (const float*)d_in[6];
    const float* Wv      = (const float*)d_in[7];
    const float* gamma   = (const float*)d_in[8];
    const float* beta    = (const float*)d_in[9];
    float* out = (float*)d_out;

    const size_t NTOK = (size_t)BB * SS;          // 4096
    // layout (54 MB): Abf[3] 24MB (Ob 16MB ALIASES it — gemm finishes reading
    // Abf before attn writes Ob; stream-ordered) | Qbf 8 | Kbf 8 | Vtb 8 | Wt 6
    u16* Abf = (u16*)d_ws;
    float* Ob = (float*)d_ws;
    u16* Qbf = Abf + 3 * NTOK * DD;
    u16* Kbf = Qbf + NTOK * DD;
    u16* Vtb = Kbf + NTOK * DD;
    u16* WtA = Vtb + NTOK * DD;

    prep<<<dim3(256, 1, 6), 256, 0, stream>>>(queries, keys, values, Wq, Wk, Wv, Abf, WtA);

    gemm_fused<<<768, 256, 0, stream>>>(Abf, WtA, Qbf, Kbf, Vtb);

    attn_mfma<<<BB * HH * (SS / 128), 256, 0, stream>>>(Qbf, Kbf, Vtb, qmask, kmask, Ob);

    ln_kernel<<<BB * SS, 256, 0, stream>>>(queries, Ob, gamma, beta, out);
}

// Round 7
// 182.650 us; speedup vs baseline: 1.0565x; 1.0565x over previous
//
#include <hip/hip_runtime.h>

#define BB   4
#define SS   1024
#define DD   1024
#define HH   16
#define DHH  64
#define LN_EPS  (1e-3f)

typedef unsigned short u16;
typedef __attribute__((ext_vector_type(8))) short bf16x8;
typedef __attribute__((ext_vector_type(4))) float f32x4;

__device__ __forceinline__ u16 f2bf(float f) {
    union { float f; unsigned int u; } v; v.f = f;
    return (u16)((v.u + 0x7FFFu + ((v.u >> 16) & 1u)) >> 16);
}

// pack two f32 -> two bf16 (RNE) in one VALU op
__device__ __forceinline__ unsigned int cvt_pk_bf16(float lo, float hi) {
    unsigned int r;
    asm("v_cvt_pk_bf16_f32 %0, %1, %2" : "=v"(r) : "v"(lo), "v"(hi));
    return r;
}

// async global->LDS, 16B per lane; lane i lands at lds + i*16 (wave-uniform
// base, no per-lane scatter — swizzle is applied to the SOURCE address).
__device__ __forceinline__ void cp16(void* lds, const void* g) {
    __builtin_amdgcn_global_load_lds(
        (const __attribute__((address_space(1))) unsigned int*)g,
        (__attribute__((address_space(3))) unsigned int*)lds, 16, 0, 0);
}

// ---------------------------------------------------------------------------
// prep: z<3 -> fp32->bf16 convert of queries/keys/values into Abf[3][4096][1024]
//       z>=3 -> W[k][n] fp32 -> Wt[n][k] bf16 (transpose+convert)
// ---------------------------------------------------------------------------
__global__ __launch_bounds__(256) void prep(const float* __restrict__ q,
                                            const float* __restrict__ k,
                                            const float* __restrict__ v,
                                            const float* __restrict__ Wq,
                                            const float* __restrict__ Wk,
                                            const float* __restrict__ Wv,
                                            u16* __restrict__ Abf,
                                            u16* __restrict__ WtA) {
    __shared__ float Ts[64][65];
    const int z = blockIdx.z;
    const int tid = threadIdx.x;
    if (z < 3) {
        const float* src = (z == 0) ? q : (z == 1) ? k : v;
        u16* dst = Abf + (size_t)z * ((size_t)BB * SS * DD);
        const int N8 = BB * SS * DD / 8;
        for (int i = blockIdx.x * 256 + tid; i < N8; i += 256 * 256) {
            const float4 f0 = ((const float4*)src)[i * 2];
            const float4 f1 = ((const float4*)src)[i * 2 + 1];
            union { u16 u[8]; uint4 o; } t;
            t.u[0] = f2bf(f0.x); t.u[1] = f2bf(f0.y);
            t.u[2] = f2bf(f0.z); t.u[3] = f2bf(f0.w);
            t.u[4] = f2bf(f1.x); t.u[5] = f2bf(f1.y);
            t.u[6] = f2bf(f1.z); t.u[7] = f2bf(f1.w);
            ((uint4*)dst)[i] = t.o;
        }
    } else {
        const float* W = (z == 3) ? Wq : (z == 4) ? Wk : Wv;
        u16* Wt = WtA + (size_t)(z - 3) * DD * DD;
        const int k0 = (blockIdx.x >> 4) * 64, n0 = (blockIdx.x & 15) * 64;
        #pragma unroll
        for (int it = 0; it < 4; ++it) {
            const int idx = tid + it * 256;
            const int r = idx >> 4, c4 = (idx & 15) * 4;
            const float4 vv = *(const float4*)&W[(size_t)(k0 + r) * DD + n0 + c4];
            Ts[r][c4 + 0] = vv.x; Ts[r][c4 + 1] = vv.y;
            Ts[r][c4 + 2] = vv.z; Ts[r][c4 + 3] = vv.w;
        }
        __syncthreads();
        const int n = tid >> 2, kc = (tid & 3) * 16;
        #pragma unroll
        for (int p = 0; p < 8; ++p) {
            const unsigned int lo = f2bf(Ts[kc + p * 2 + 0][n]);
            const unsigned int hi = f2bf(Ts[kc + p * 2 + 1][n]);
            *(unsigned int*)&Wt[(size_t)(n0 + n) * DD + k0 + kc + p * 2] = lo | (hi << 16);
        }
    }
}

// ---------------------------------------------------------------------------
// Fused QKV projection GEMM — 128x128 tile, BK=64, 4 waves (2x2), 256 thr.
// m97 structure: single-buffer LDS (32 KB), global_load_lds staging, 2
// barriers per K-step. __launch_bounds__(256,3) forces <=170 regs/wave ->
// 3 blocks/CU co-resident (12 waves/CU): cross-block overlap hides the
// barrier drain (m114).
// Grid = 768 blocks (3z x 32m x 8n), XCD-swizzled, = 3 clean rounds.
//   z=0: Q*(0.125*log2e) [b][h][s][dh] (exp2-domain); z=1: K; z=2: V^T.
// ---------------------------------------------------------------------------
__global__ __launch_bounds__(256, 3) void gemm_fused(const u16* __restrict__ Abf,
                                                     const u16* __restrict__ WtA,
                                                     u16* __restrict__ Qbf,
                                                     u16* __restrict__ Kbf,
                                                     u16* __restrict__ Vtb) {
    __shared__ u16 As[128 * 64];   // 16 KB, XOR-swizzled chunks
    __shared__ u16 Bs[128 * 64];

    const int bid = blockIdx.x;
    const int swz = (bid & 7) * 96 + (bid >> 3);   // bijective, 768 % 8 == 0
    const int z   = swz >> 8;                      // 256 tiles per z
    const int rem = swz & 255;
    const int m0  = (rem >> 3) * 128;              // m-major within XCD: B panels reused
    const int n0  = (rem & 7) * 128;

    const u16* A  = Abf + (size_t)z * ((size_t)BB * SS * DD);
    const u16* Bm = WtA + (size_t)z * (DD * DD);

    const int tid  = threadIdx.x;
    const int wave = tid >> 6, lane = tid & 63;
    const int ln = lane & 15, quad = lane >> 4;
    const int mw = (wave & 1) * 64, nw = (wave >> 1) * 64;

    // staging decomposition for slot l = w*256+tid: row r = w*32 + (tid>>3),
    // stored chunk cs = tid&7 holds global chunk c = cs ^ (r&7); r&7 and c
    // are w-invariant (w*32 % 8 == 0) -> single base + uniform w offset.
    const int r0 = tid >> 3;
    const int c0 = (tid & 7) ^ (r0 & 7);
    const u16* srcA0 = A  + (size_t)(m0 + r0) * DD + c0 * 8;
    const u16* srcB0 = Bm + (size_t)(n0 + r0) * DD + c0 * 8;

    f32x4 acc[4][4] = {};

    for (int t = 0; t < 16; ++t) {
        const int koff = t * 64;
        __syncthreads();
        #pragma unroll
        for (int w = 0; w < 4; ++w) {
            cp16(&As[(w * 256 + wave * 64) * 8], srcA0 + (size_t)w * 32 * DD + koff);
            cp16(&Bs[(w * 256 + wave * 64) * 8], srcB0 + (size_t)w * 32 * DD + koff);
        }
        __syncthreads();

        #pragma unroll
        for (int kk = 0; kk < 2; ++kk) {
            bf16x8 af[4], bfv[4];
            #pragma unroll
            for (int i = 0; i < 4; ++i) {
                const int r = mw + i * 16 + ln;
                af[i] = *(const bf16x8*)&As[((r << 3) + ((kk * 4 + quad) ^ (r & 7))) << 3];
            }
            #pragma unroll
            for (int j = 0; j < 4; ++j) {
                const int r = nw + j * 16 + ln;
                bfv[j] = *(const bf16x8*)&Bs[((r << 3) + ((kk * 4 + quad) ^ (r & 7))) << 3];
            }
            __builtin_amdgcn_s_setprio(1);
            #pragma unroll
            for (int i = 0; i < 4; ++i)
                #pragma unroll
                for (int j = 0; j < 4; ++j)
                    acc[i][j] = __builtin_amdgcn_mfma_f32_16x16x32_bf16(af[i], bfv[j], acc[i][j], 0, 0, 0);
            __builtin_amdgcn_s_setprio(0);
        }
    }

    if (z < 2) {
        u16* C = (z == 0) ? Qbf : Kbf;
        // z=0: fold 1/sqrt(64) AND log2(e) into Q so attn uses exp2 directly
        const float scale = (z == 0) ? 0.18033688f : 1.0f;
        #pragma unroll
        for (int i = 0; i < 4; ++i) {
            const int mbase = m0 + mw + i * 16 + quad * 4;
            const int bb = mbase >> 10, sb = mbase & 1023;
            #pragma unroll
            for (int j = 0; j < 4; ++j) {
                const int n = n0 + nw + j * 16 + ln;
                const int hh = n >> 6, dh = n & 63;
                #pragma unroll
                for (int r = 0; r < 4; ++r)
                    C[(((size_t)bb * HH + hh) * SS + sb + r) * DHH + dh] =
                        f2bf(acc[i][j][r] * scale);
            }
        }
    } else {
        #pragma unroll
        for (int i = 0; i < 4; ++i) {
            const int mbase = m0 + mw + i * 16 + quad * 4;
            const int bb = mbase >> 10, sb = mbase & 1023;
            #pragma unroll
            for (int j = 0; j < 4; ++j) {
                const int n = n0 + nw + j * 16 + ln;
                const int hh = n >> 6, dh = n & 63;
                uint2 pk;
                pk.x = cvt_pk_bf16(acc[i][j][0], acc[i][j][1]);
                pk.y = cvt_pk_bf16(acc[i][j][2], acc[i][j][3]);
                *(uint2*)&Vtb[(((size_t)bb * HH + hh) * DHH + dh) * SS + sb] = pk;
            }
        }
    }
}

// ---------------------------------------------------------------------------
// Flash attention. 8 waves (512 thr), QBLK=128 (16 q-rows/wave), KVBLK=64.
// Grid = 512 blocks = 2 blocks/CU, 16 waves/CU (R5-proven geometry).
// TRI-buffered K/V: buffer staged at kt+2 was last read at kt-1, so ONE
// barrier per iteration (fused with the counted vmcnt wait) preserves the
// reuse-distance-3 invariant -> 16 barriers instead of 31. Stage issued
// BEFORE compute so HBM latency hides under QK^T+PV. vmcnt(2) steady state,
// 0 only at the tail. Swapped QK^T (mfma(K,Q)) -> lane-local P segment,
// cvt_pk + ds_write_b64 to Ps. Q direct global->reg. kmask once as floats.
// LDS 69 KB -> 2 blocks/CU.
// ---------------------------------------------------------------------------
__global__ __launch_bounds__(512) void attn_mfma(const u16* __restrict__ Qg,
                                                 const u16* __restrict__ Kg,
                                                 const u16* __restrict__ Vtg,
                                                 const int* __restrict__ qmask,
                                                 const int* __restrict__ kmask,
                                                 float* __restrict__ O) {
    __shared__ u16 Ps[128 * 68];         // P spill, pitch 68 (b64-aligned rows)
    __shared__ u16 Ks[3][64 * 64];       // [key][dh] swizzled chunks, tri-buf
    __shared__ u16 Vs[3][64 * 64];       // [dh][key] swizzled chunks, tri-buf
    __shared__ float kmLds[SS];          // key-mask as float 0/1

    const int bid  = blockIdx.x;
    const int xcd  = bid & 7;
    const int rest = bid >> 3;               // 0..63
    const int bh   = (rest & 7) * 8 + xcd;   // 0..63, bh%8==xcd
    const int qt   = rest >> 3;              // 0..7
    const int b    = bh >> 4, h = bh & 15;
    const int q0   = qt * 128;
    const int tid  = threadIdx.x;
    const int wave = tid >> 6, lane = tid & 63;
    const int ln = lane & 15, quad = lane >> 4;
    const size_t bhs = (size_t)b * HH + h;

    // staging: 512 threads x 16B = 8KB = one full 64x64 bf16 tile each for K,V
    const int sr = tid >> 3, scsrc = (tid & 7) ^ ((tid >> 3) & 7);
    const u16* kSrc = &Kg[(bhs * SS + sr) * DHH + scsrc * 8];          // + t*64 rows
    const u16* vSrc = &Vtg[(bhs * DHH + sr) * SS + scsrc * 8];         // + t*64 cols
    auto stageKV = [&](int cb, int t) {
        cp16(&Ks[cb][wave * 512], kSrc + (size_t)t * 64 * DHH);
        cp16(&Vs[cb][wave * 512], vSrc + t * 64);
    };

    // --- prologue ---
    // Q fragment direct to registers: row q0+wave*16+ln, d = kk*32 + quad*8
    const u16* qrow = &Qg[(bhs * SS + q0 + wave * 16 + ln) * DHH];
    const bf16x8 qf0 = *(const bf16x8*)&qrow[quad * 8];
    const bf16x8 qf1 = *(const bf16x8*)&qrow[32 + quad * 8];
    asm volatile("" ::: "memory");       // pin qf issue before staging
    if (wave < 4)
        cp16(&kmLds[wave * 256], &kmask[b * SS + (wave * 64 + lane) * 4]);
    stageKV(0, 0);
    stageKV(1, 1);
    asm volatile("s_waitcnt vmcnt(2)" ::: "memory");   // qf+km+tile0 landed
    __builtin_amdgcn_s_barrier();

    // kmask int -> float in place (each thread owns 2)
    {
        const int2 iv = *(const int2*)&kmLds[tid * 2];
        float2 fv; fv.x = (float)iv.x; fv.y = (float)iv.y;
        *(float2*)&kmLds[tid * 2] = fv;
    }
    asm volatile("s_waitcnt lgkmcnt(0)" ::: "memory");
    __builtin_amdgcn_s_barrier();

    // hoisted swizzled LDS element offsets: row nt*16+ln, chunk kk*4+quad
    int off[4][2];
    #pragma unroll
    for (int nt = 0; nt < 4; ++nt) {
        const int r = nt * 16 + ln;
        off[nt][0] = ((r << 3) + ((0 + quad) ^ (r & 7))) << 3;
        off[nt][1] = ((r << 3) + ((4 + quad) ^ (r & 7))) << 3;
    }

    f32x4 o[4] = {};
    float lsum = 0.f;
    const f32x4 zero = {0.f, 0.f, 0.f, 0.f};
    const int prow = (wave * 16 + ln) * 68;   // this lane's Ps row base

    int cbC = 0, cbS = 2;                     // compute buf (kt%3), stage buf ((kt+2)%3)
    for (int kt = 0; kt < SS / 64; ++kt) {
        // stage kt+2 first: its buffer was last read at kt-1 (prev barrier
        // guarantees all waves are past it); HBM latency hides under compute.
        if (kt + 2 < SS / 64) stageKV(cbS, kt + 2);

        const u16* Kc = Ks[cbC];
        const u16* Vc = Vs[cbC];

        // S^T = K @ Q^T (Q pre-scaled by 0.125*log2e); p = fm * exp2(s)
        // out: k-row = nt*16 + quad*4 + r, q-col = wave*16 + ln
        #pragma unroll
        for (int nt = 0; nt < 4; ++nt) {
            const bf16x8 k0f = *(const bf16x8*)&Kc[off[nt][0]];
            const bf16x8 k1f = *(const bf16x8*)&Kc[off[nt][1]];
            f32x4 sacc = __builtin_amdgcn_mfma_f32_16x16x32_bf16(k0f, qf0, zero, 0, 0, 0);
            sacc = __builtin_amdgcn_mfma_f32_16x16x32_bf16(k1f, qf1, sacc, 0, 0, 0);
            const float4 fm = *(const float4*)&kmLds[kt * 64 + nt * 16 + quad * 4];
            const float p0 = fm.x * __builtin_amdgcn_exp2f(sacc[0]);
            const float p1 = fm.y * __builtin_amdgcn_exp2f(sacc[1]);
            const float p2 = fm.z * __builtin_amdgcn_exp2f(sacc[2]);
            const float p3 = fm.w * __builtin_amdgcn_exp2f(sacc[3]);
            lsum += (p0 + p1) + (p2 + p3);
            uint2 pk;
            pk.x = cvt_pk_bf16(p0, p1);
            pk.y = cvt_pk_bf16(p2, p3);
            *(uint2*)&Ps[prow + nt * 16 + quad * 4] = pk;   // 4 consecutive cols
        }
        // Ps rows are wave-private; same-wave lgkm ordering covers the RAW.

        // O += P @ V
        __builtin_amdgcn_s_setprio(1);
        #pragma unroll
        for (int kk2 = 0; kk2 < 2; ++kk2) {
            const bf16x8 pf = *(const bf16x8*)&Ps[prow + kk2 * 32 + quad * 8];
            #pragma unroll
            for (int nt2 = 0; nt2 < 4; ++nt2) {
                const bf16x8 vf = *(const bf16x8*)&Vc[off[nt2][kk2]];
                o[nt2] = __builtin_amdgcn_mfma_f32_16x16x32_bf16(pf, vf, o[nt2], 0, 0, 0);
            }
        }
        __builtin_amdgcn_s_setprio(0);

        // single fused wait+barrier: "all waves finished compute(kt)" AND
        // "tile kt+1 landed for all waves" (counted per-wave vmcnt + barrier)
        if (kt < SS / 64 - 1) {
            if (kt + 2 < SS / 64) asm volatile("s_waitcnt vmcnt(2)" ::: "memory");
            else                  asm volatile("s_waitcnt vmcnt(0)" ::: "memory");
            __builtin_amdgcn_s_barrier();
        }
        cbC = (cbC == 2) ? 0 : cbC + 1;
        cbS = (cbS == 2) ? 0 : cbS + 1;
    }

    // epilogue: quad-reduce lane-local l (q = wave*16+ln), normalize, store
    lsum += __shfl_xor(lsum, 16);
    lsum += __shfl_xor(lsum, 32);
    #pragma unroll
    for (int r = 0; r < 4; ++r) {
        const int qloc = quad * 4 + r;
        const float l = __shfl(lsum, qloc);        // lane qloc holds full sum
        const int q = q0 + wave * 16 + qloc;
        const float scale = (float)qmask[b * SS + q] / l;
        #pragma unroll
        for (int nt2 = 0; nt2 < 4; ++nt2)
            O[((size_t)b * SS + q) * DD + h * DHH + nt2 * 16 + ln] = o[nt2][r] * scale;
    }
}

// ---------------------------------------------------------------------------
// residual + LayerNorm over D=1024. ONE WAVE per (b,s) row: 64 lanes x 4
// float4 = 1024 floats; reductions are pure __shfl_xor (no LDS, no
// __syncthreads). 4 rows per 256-thread block, grid = 1024.
// ---------------------------------------------------------------------------
__global__ __launch_bounds__(256) void ln_kernel(const float* __restrict__ Qin,
                                                 const float* __restrict__ attn,
                                                 const float* __restrict__ gamma,
                                                 const float* __restrict__ beta,
                                                 float* __restrict__ out) {
    const int tid = threadIdx.x;
    const int wid = tid >> 6, lane = tid & 63;
    const int row = blockIdx.x * 4 + wid;
    const float4* qp = (const float4*)Qin + (size_t)row * 256;
    const float4* ap = (const float4*)attn + (size_t)row * 256;

    float4 v[4];
    float sum = 0.f;
    #pragma unroll
    for (int i = 0; i < 4; ++i) {
        const float4 qv = qp[lane + 64 * i];
        const float4 av = ap[lane + 64 * i];
        float4 t;
        t.x = qv.x + av.x; t.y = qv.y + av.y;
        t.z = qv.z + av.z; t.w = qv.w + av.w;
        v[i] = t;
        sum += (t.x + t.y) + (t.z + t.w);
    }
    #pragma unroll
    for (int off = 1; off < 64; off <<= 1) sum += __shfl_xor(sum, off);
    const float mean = sum * (1.0f / DD);

    float vs = 0.f;
    #pragma unroll
    for (int i = 0; i < 4; ++i) {
        const float dx = v[i].x - mean, dy = v[i].y - mean;
        const float dz = v[i].z - mean, dw = v[i].w - mean;
        vs += (dx * dx + dy * dy) + (dz * dz + dw * dw);
    }
    #pragma unroll
    for (int off = 1; off < 64; off <<= 1) vs += __shfl_xor(vs, off);
    const float inv = rsqrtf(vs * (1.0f / DD) + LN_EPS);

    #pragma unroll
    for (int i = 0; i < 4; ++i) {
        const float4 g  = ((const float4*)gamma)[lane + 64 * i];
        const float4 bt = ((const float4*)beta)[lane + 64 * i];
        float4 ov;
        ov.x = g.x * (v[i].x - mean) * inv + bt.x;
        ov.y = g.y * (v[i].y - mean) * inv + bt.y;
        ov.z = g.z * (v[i].z - mean) * inv + bt.z;
        ov.w = g.w * (v[i].w - mean) * inv + bt.w;
        ((float4*)out)[(size_t)row * 256 + lane + 64 * i] = ov;
    }
}

// ---------------------------------------------------------------------------
extern "C" void kernel_launch(void* const* d_in, const int* in_sizes, int n_in,
                              void* d_out, int out_size, void* d_ws, size_t ws_size,
                              hipStream_t stream) {
    const float* queries = (const float*)d_in[0];
    const float* keys    = (const float*)d_in[1];
    const float* values  = (const float*)d_in[2];
    const int*   qmask   = (const int*)d_in[3];
    const int*   kmask   = (const int*)d_in[4];
    const float* Wq      = (const float*)d_in[5];
    const float* Wk      = (const float*)d_in[6];
    const float* Wv      = (const float*)d_in[7];
    const float* gamma   = (const float*)d_in[8];
    const float* beta    = (const float*)d_in[9];
    float* out = (float*)d_out;

    const size_t NTOK = (size_t)BB * SS;          // 4096
    // layout (54 MB): Abf[3] 24MB (Ob 16MB ALIASES it — gemm finishes reading
    // Abf before attn writes Ob; stream-ordered) | Qbf 8 | Kbf 8 | Vtb 8 | Wt 6
    u16* Abf = (u16*)d_ws;
    float* Ob = (float*)d_ws;
    u16* Qbf = Abf + 3 * NTOK * DD;
    u16* Kbf = Qbf + NTOK * DD;
    u16* Vtb = Kbf + NTOK * DD;
    u16* WtA = Vtb + NTOK * DD;

    prep<<<dim3(256, 1, 6), 256, 0, stream>>>(queries, keys, values, Wq, Wk, Wv, Abf, WtA);

    gemm_fused<<<768, 256, 0, stream>>>(Abf, WtA, Qbf, Kbf, Vtb);

    attn_mfma<<<BB * HH * (SS / 128), 512, 0, stream>>>(Qbf, Kbf, Vtb, qmask, kmask, Ob);

    ln_kernel<<<BB * SS / 4, 256, 0, stream>>>(queries, Ob, gamma, beta, out);
}